// Round 6
// baseline (42.950 us; speedup 1.0000x reference)
//
#include <hip/hip_runtime.h>

#define HW 512
#define D1_PITCH 197   // 65 px * 3 ch = 195 dwords + 2 pad; 197 % 32 = 5 -> 2-way banks (free)

__device__ __forceinline__ float prelu(float x, float a) { return x >= 0.f ? x : a * x; }

// Shared tile math for both passes: stage d1[17][65] (one barrier elsewhere),
// then each thread computes s for 4 consecutive px of row h.
// Pass 1 sums s; pass 2 scales s by y and writes out.

// ---- K1: partial sums only. grid (8, 32, 8) x 256 thr. Writes 24 KB total. ----
__global__ __launch_bounds__(256) void k1_sums(
    const float* __restrict__ in1, const float* __restrict__ in2, const float* __restrict__ in3,
    const float* __restrict__ Wd, const float* __restrict__ bd, const float* __restrict__ ad,
    const float* __restrict__ Wu, const float* __restrict__ bu, const float* __restrict__ au,
    float* __restrict__ partials)
{
    __shared__ float d1[17 * D1_PITCH];
    __shared__ float red[4][3];

    const int tid   = threadIdx.x;
    const int bx    = blockIdx.x;      // 0..7  col tile (64 px)
    const int by    = blockIdx.y;      // 0..31 row tile (16 px)
    const int batch = blockIdx.z;      // 0..7
    const int h0    = by * 16;
    const int w0b   = bx * 64;

    float wd[9], wu[9];
    #pragma unroll
    for (int k = 0; k < 9; k++) { wd[k] = Wd[k]; wu[k] = Wu[k]; }
    const float bd0 = bd[0], bd1 = bd[1], bd2 = bd[2];
    const float ad0 = ad[0], ad1 = ad[1], ad2 = ad[2];
    const float bu0 = bu[0], bu1 = bu[1], bu2 = bu[2];
    const float au0 = au[0], au1 = au[1], au2 = au[2];
    const float cu0 = prelu(bu0, au0), cu1 = prelu(bu1, au1), cu2 = prelu(bu2, au2);

    // Phase A: stage d1 tile (rows h0..h0+16, cols w0b..w0b+64)
    #pragma unroll
    for (int k = 0; k < 5; ++k) {
        const int e = k * 256 + tid;
        if (e < 17 * 65) {
            const int dr = e / 65, dc = e - dr * 65;
            const int gh = h0 + dr, gw = w0b + dc;
            float v0 = -INFINITY, v1 = -INFINITY, v2 = -INFINITY;
            if (gh < HW && gw < HW) {
                const float* p = in1 + ((size_t)((batch * 1024 + 2 * gh) * 1024 + 2 * gw)) * 3;
                const float x0 = p[0], x1 = p[1], x2 = p[2];
                v0 = prelu(x0 * wd[0] + x1 * wd[3] + x2 * wd[6] + bd0, ad0);
                v1 = prelu(x0 * wd[1] + x1 * wd[4] + x2 * wd[7] + bd1, ad1);
                v2 = prelu(x0 * wd[2] + x1 * wd[5] + x2 * wd[8] + bd2, ad2);
            }
            float* q = d1 + dr * D1_PITCH + dc * 3;
            q[0] = v0; q[1] = v1; q[2] = v2;
        }
    }
    __syncthreads();

    // Phase B: 4 px/thread
    const int r  = tid >> 4;
    const int cg = tid & 15;
    const int h  = h0 + r;
    const int w0 = w0b + cg * 4;

    const float* in2p = in2 + ((size_t)((batch * HW + h) * HW + w0)) * 3;
    float i2v[12];
    #pragma unroll
    for (int k = 0; k < 3; ++k)
        *reinterpret_cast<float4*>(&i2v[4 * k]) = reinterpret_cast<const float4*>(in2p)[k];

    const int he = h + (h & 1);
    const bool heok = he < HW;
    const int w3 = w0 >> 1;
    float ud[3][3];
    #pragma unroll
    for (int k = 0; k < 3; ++k) {
        float u0 = cu0, u1 = cu1, u2 = cu2;
        if (heok && (w3 + k) < 256) {
            const float* p = in3 + ((size_t)((batch * 256 + (he >> 1)) * 256 + w3 + k)) * 3;
            const float x0 = p[0], x1 = p[1], x2 = p[2];
            u0 = fmaxf(u0, prelu(x0 * wu[0] + x1 * wu[3] + x2 * wu[6] + bu0, au0));
            u1 = fmaxf(u1, prelu(x0 * wu[1] + x1 * wu[4] + x2 * wu[7] + bu1, au1));
            u2 = fmaxf(u2, prelu(x0 * wu[2] + x1 * wu[5] + x2 * wu[8] + bu2, au2));
        }
        ud[k][0] = u0; ud[k][1] = u1; ud[k][2] = u2;
    }

    const int baseA = r * D1_PITCH + cg * 12;
    const int baseB = baseA + D1_PITCH;
    float pA0 = d1[baseA + 0], pA1 = d1[baseA + 1], pA2 = d1[baseA + 2];
    float pB0 = d1[baseB + 0], pB1 = d1[baseB + 1], pB2 = d1[baseB + 2];

    float sum0 = 0.f, sum1 = 0.f, sum2 = 0.f;
    #pragma unroll
    for (int j = 0; j < 4; ++j) {
        const int o = 3 * (j + 1);
        const float cA0 = d1[baseA + o], cA1 = d1[baseA + o + 1], cA2 = d1[baseA + o + 2];
        const float cB0 = d1[baseB + o], cB1 = d1[baseB + o + 1], cB2 = d1[baseB + o + 2];
        const int uk = (j + 1) >> 1;
        sum0 += fmaxf(fmaxf(pA0, cA0), fmaxf(pB0, cB0)) + i2v[3 * j + 0] + ud[uk][0];
        sum1 += fmaxf(fmaxf(pA1, cA1), fmaxf(pB1, cB1)) + i2v[3 * j + 1] + ud[uk][1];
        sum2 += fmaxf(fmaxf(pA2, cA2), fmaxf(pB2, cB2)) + i2v[3 * j + 2] + ud[uk][2];
        pA0 = cA0; pA1 = cA1; pA2 = cA2;
        pB0 = cB0; pB1 = cB1; pB2 = cB2;
    }

    #pragma unroll
    for (int off = 32; off > 0; off >>= 1) {
        sum0 += __shfl_down(sum0, off);
        sum1 += __shfl_down(sum1, off);
        sum2 += __shfl_down(sum2, off);
    }
    if ((tid & 63) == 0) { red[tid >> 6][0] = sum0; red[tid >> 6][1] = sum1; red[tid >> 6][2] = sum2; }
    __syncthreads();
    if (tid == 0) {
        const int pid = (batch * 32 + by) * 8 + bx;
        partials[pid * 3 + 0] = red[0][0] + red[1][0] + red[2][0] + red[3][0];
        partials[pid * 3 + 1] = red[0][1] + red[1][1] + red[2][1] + red[3][1];
        partials[pid * 3 + 2] = red[0][2] + red[1][2] + red[2][2] + red[3][2];
    }
}

// ---- K2: recompute s (inputs now L3-resident), gate redundantly, write y*s. ----
__global__ __launch_bounds__(256) void k2_recompute_scale(
    const float* __restrict__ in1, const float* __restrict__ in2, const float* __restrict__ in3,
    const float* __restrict__ Wd, const float* __restrict__ bd, const float* __restrict__ ad,
    const float* __restrict__ Wu, const float* __restrict__ bu, const float* __restrict__ au,
    const float* __restrict__ partials,
    const float* __restrict__ Wc, const float* __restrict__ bc, const float* __restrict__ ag,
    float* __restrict__ out)
{
    __shared__ float d1[17 * D1_PITCH];
    __shared__ float ybuf[3];

    const int tid   = threadIdx.x;
    const int bx    = blockIdx.x;
    const int by    = blockIdx.y;
    const int batch = blockIdx.z;
    const int h0    = by * 16;
    const int w0b   = bx * 64;

    // gate: wave 0 reduces this batch's 256 partials in a fixed tree (identical
    // order in every block -> bitwise-identical y per batch). Runs concurrently
    // with phase-A staging; the staging barrier publishes ybuf too.
    if (tid < 64) {
        const float* pw = partials + batch * 256 * 3;
        float g0 = 0.f, g1 = 0.f, g2 = 0.f;
        #pragma unroll
        for (int k = 0; k < 4; ++k) {
            const float* p = pw + (tid + 64 * k) * 3;
            g0 += p[0]; g1 += p[1]; g2 += p[2];
        }
        #pragma unroll
        for (int off = 32; off > 0; off >>= 1) {
            g0 += __shfl_down(g0, off);
            g1 += __shfl_down(g1, off);
            g2 += __shfl_down(g2, off);
        }
        if (tid == 0) {
            const float inv_n = 1.f / (float)(HW * HW);
            g0 *= inv_n; g1 *= inv_n; g2 *= inv_n;
            const float x0 = prelu(g0 * Wc[0] + g1 * Wc[3] + g2 * Wc[6] + bc[0], ag[0]);
            const float x1 = prelu(g0 * Wc[1] + g1 * Wc[4] + g2 * Wc[7] + bc[1], ag[1]);
            const float x2 = prelu(g0 * Wc[2] + g1 * Wc[5] + g2 * Wc[8] + bc[2], ag[2]);
            const float q0 = x0 * Wc[0] + x1 * Wc[3] + x2 * Wc[6] + bc[0];
            const float q1 = x0 * Wc[1] + x1 * Wc[4] + x2 * Wc[7] + bc[1];
            const float q2 = x0 * Wc[2] + x1 * Wc[5] + x2 * Wc[8] + bc[2];
            const float m  = fmaxf(q0, fmaxf(q1, q2));
            const float e0 = expf(q0 - m), e1 = expf(q1 - m), e2 = expf(q2 - m);
            const float inv = 1.f / (e0 + e1 + e2);
            ybuf[0] = e0 * inv; ybuf[1] = e1 * inv; ybuf[2] = e2 * inv;
        }
    }

    float wd[9], wu[9];
    #pragma unroll
    for (int k = 0; k < 9; k++) { wd[k] = Wd[k]; wu[k] = Wu[k]; }
    const float bd0 = bd[0], bd1 = bd[1], bd2 = bd[2];
    const float ad0 = ad[0], ad1 = ad[1], ad2 = ad[2];
    const float bu0 = bu[0], bu1 = bu[1], bu2 = bu[2];
    const float au0 = au[0], au1 = au[1], au2 = au[2];
    const float cu0 = prelu(bu0, au0), cu1 = prelu(bu1, au1), cu2 = prelu(bu2, au2);

    #pragma unroll
    for (int k = 0; k < 5; ++k) {
        const int e = k * 256 + tid;
        if (e < 17 * 65) {
            const int dr = e / 65, dc = e - dr * 65;
            const int gh = h0 + dr, gw = w0b + dc;
            float v0 = -INFINITY, v1 = -INFINITY, v2 = -INFINITY;
            if (gh < HW && gw < HW) {
                const float* p = in1 + ((size_t)((batch * 1024 + 2 * gh) * 1024 + 2 * gw)) * 3;
                const float x0 = p[0], x1 = p[1], x2 = p[2];
                v0 = prelu(x0 * wd[0] + x1 * wd[3] + x2 * wd[6] + bd0, ad0);
                v1 = prelu(x0 * wd[1] + x1 * wd[4] + x2 * wd[7] + bd1, ad1);
                v2 = prelu(x0 * wd[2] + x1 * wd[5] + x2 * wd[8] + bd2, ad2);
            }
            float* q = d1 + dr * D1_PITCH + dc * 3;
            q[0] = v0; q[1] = v1; q[2] = v2;
        }
    }
    __syncthreads();

    const int r  = tid >> 4;
    const int cg = tid & 15;
    const int h  = h0 + r;
    const int w0 = w0b + cg * 4;

    const float* in2p = in2 + ((size_t)((batch * HW + h) * HW + w0)) * 3;
    float i2v[12];
    #pragma unroll
    for (int k = 0; k < 3; ++k)
        *reinterpret_cast<float4*>(&i2v[4 * k]) = reinterpret_cast<const float4*>(in2p)[k];

    const int he = h + (h & 1);
    const bool heok = he < HW;
    const int w3 = w0 >> 1;
    float ud[3][3];
    #pragma unroll
    for (int k = 0; k < 3; ++k) {
        float u0 = cu0, u1 = cu1, u2 = cu2;
        if (heok && (w3 + k) < 256) {
            const float* p = in3 + ((size_t)((batch * 256 + (he >> 1)) * 256 + w3 + k)) * 3;
            const float x0 = p[0], x1 = p[1], x2 = p[2];
            u0 = fmaxf(u0, prelu(x0 * wu[0] + x1 * wu[3] + x2 * wu[6] + bu0, au0));
            u1 = fmaxf(u1, prelu(x0 * wu[1] + x1 * wu[4] + x2 * wu[7] + bu1, au1));
            u2 = fmaxf(u2, prelu(x0 * wu[2] + x1 * wu[5] + x2 * wu[8] + bu2, au2));
        }
        ud[k][0] = u0; ud[k][1] = u1; ud[k][2] = u2;
    }

    const int baseA = r * D1_PITCH + cg * 12;
    const int baseB = baseA + D1_PITCH;
    float pA0 = d1[baseA + 0], pA1 = d1[baseA + 1], pA2 = d1[baseA + 2];
    float pB0 = d1[baseB + 0], pB1 = d1[baseB + 1], pB2 = d1[baseB + 2];

    float s[4][3];
    #pragma unroll
    for (int j = 0; j < 4; ++j) {
        const int o = 3 * (j + 1);
        const float cA0 = d1[baseA + o], cA1 = d1[baseA + o + 1], cA2 = d1[baseA + o + 2];
        const float cB0 = d1[baseB + o], cB1 = d1[baseB + o + 1], cB2 = d1[baseB + o + 2];
        const int uk = (j + 1) >> 1;
        s[j][0] = fmaxf(fmaxf(pA0, cA0), fmaxf(pB0, cB0)) + i2v[3 * j + 0] + ud[uk][0];
        s[j][1] = fmaxf(fmaxf(pA1, cA1), fmaxf(pB1, cB1)) + i2v[3 * j + 1] + ud[uk][1];
        s[j][2] = fmaxf(fmaxf(pA2, cA2), fmaxf(pB2, cB2)) + i2v[3 * j + 2] + ud[uk][2];
        pA0 = cA0; pA1 = cA1; pA2 = cA2;
        pB0 = cB0; pB1 = cB1; pB2 = cB2;
    }

    const float ym[3] = { ybuf[0], ybuf[1], ybuf[2] };
    float* outp = out + ((size_t)((batch * HW + h) * HW + w0)) * 3;
    #pragma unroll
    for (int k = 0; k < 3; ++k) {
        float4 v;
        v.x = s[(4 * k + 0) / 3][(4 * k + 0) % 3] * ym[(4 * k + 0) % 3];
        v.y = s[(4 * k + 1) / 3][(4 * k + 1) % 3] * ym[(4 * k + 1) % 3];
        v.z = s[(4 * k + 2) / 3][(4 * k + 2) % 3] * ym[(4 * k + 2) % 3];
        v.w = s[(4 * k + 3) / 3][(4 * k + 3) % 3] * ym[(4 * k + 3) % 3];
        reinterpret_cast<float4*>(outp)[k] = v;
    }
}

extern "C" void kernel_launch(void* const* d_in, const int* in_sizes, int n_in,
                              void* d_out, int out_size, void* d_ws, size_t ws_size,
                              hipStream_t stream)
{
    const float* in1 = (const float*)d_in[0];
    const float* in2 = (const float*)d_in[1];
    const float* in3 = (const float*)d_in[2];
    const float* Wd  = (const float*)d_in[3];
    const float* bd  = (const float*)d_in[4];
    const float* ad  = (const float*)d_in[5];
    const float* Wu  = (const float*)d_in[6];
    const float* bu  = (const float*)d_in[7];
    const float* au  = (const float*)d_in[8];
    const float* Wc  = (const float*)d_in[9];
    const float* bc  = (const float*)d_in[10];
    const float* ag  = (const float*)d_in[11];
    float* out = (float*)d_out;
    float* partials = (float*)d_ws;     // 2048 * 3 floats

    k1_sums<<<dim3(8, 32, 8), 256, 0, stream>>>(in1, in2, in3, Wd, bd, ad, Wu, bu, au, partials);
    k2_recompute_scale<<<dim3(8, 32, 8), 256, 0, stream>>>(in1, in2, in3, Wd, bd, ad, Wu, bu, au,
                                                           partials, Wc, bc, ag, out);
}

// Round 7
// 38.959 us; speedup vs baseline: 1.1024x; 1.1024x over previous
//
#include <hip/hip_runtime.h>

#define HW 512
#define PITCH 200   // dwords per d1 LDS row; multiple of 4 -> 16B-aligned float4 stores

__device__ __forceinline__ float prelu(float x, float a) { return x >= 0.f ? x : a * x; }

// Two-pass fused op. MODE 0: per-block partial sums of s = i1+i2+i3 (writes 24 KB).
// MODE 1: redundant deterministic gate from partials, recompute s (inputs L3-hot), write y*s.
// Both passes: 16x64 output tile per 256-thread block, grid (8,32,8).
// All global loads are branch-free with clamped in-buffer addresses; validity is
// folded in afterwards (-inf / cu overrides) so loads issue back-to-back (MLP).
template<int MODE>
__global__ __launch_bounds__(256, 4) void pass_kernel(
    const float* __restrict__ in1, const float* __restrict__ in2, const float* __restrict__ in3,
    const float* __restrict__ Wd, const float* __restrict__ bd, const float* __restrict__ ad,
    const float* __restrict__ Wu, const float* __restrict__ bu, const float* __restrict__ au,
    float* __restrict__ partials,
    const float* __restrict__ Wc, const float* __restrict__ bc, const float* __restrict__ ag,
    float* __restrict__ out)
{
    __shared__ float d1[17 * PITCH];
    __shared__ float red[4][3];
    __shared__ float ybuf[3];

    const int tid   = threadIdx.x;
    const int bx    = blockIdx.x;      // 0..7  col tile (64 px)
    const int by    = blockIdx.y;      // 0..31 row tile (16 px)
    const int batch = blockIdx.z;      // 0..7
    const int h0    = by * 16;
    const int w0b   = bx * 64;

    // ---- MODE 1: gate on wave 0, overlapped with staging; barrier publishes ybuf ----
    if (MODE == 1 && tid < 64) {
        const float* pw = partials + batch * 256 * 3;
        float g0 = 0.f, g1 = 0.f, g2 = 0.f;
        #pragma unroll
        for (int k = 0; k < 4; ++k) {
            const float* p = pw + (tid + 64 * k) * 3;
            g0 += p[0]; g1 += p[1]; g2 += p[2];
        }
        #pragma unroll
        for (int off = 32; off > 0; off >>= 1) {
            g0 += __shfl_down(g0, off);
            g1 += __shfl_down(g1, off);
            g2 += __shfl_down(g2, off);
        }
        if (tid == 0) {
            const float inv_n = 1.f / (float)(HW * HW);
            g0 *= inv_n; g1 *= inv_n; g2 *= inv_n;
            const float x0 = prelu(g0 * Wc[0] + g1 * Wc[3] + g2 * Wc[6] + bc[0], ag[0]);
            const float x1 = prelu(g0 * Wc[1] + g1 * Wc[4] + g2 * Wc[7] + bc[1], ag[1]);
            const float x2 = prelu(g0 * Wc[2] + g1 * Wc[5] + g2 * Wc[8] + bc[2], ag[2]);
            const float q0 = x0 * Wc[0] + x1 * Wc[3] + x2 * Wc[6] + bc[0];
            const float q1 = x0 * Wc[1] + x1 * Wc[4] + x2 * Wc[7] + bc[1];
            const float q2 = x0 * Wc[2] + x1 * Wc[5] + x2 * Wc[8] + bc[2];
            const float m  = fmaxf(q0, fmaxf(q1, q2));
            const float e0 = expf(q0 - m), e1 = expf(q1 - m), e2 = expf(q2 - m);
            const float inv = 1.f / (e0 + e1 + e2);
            ybuf[0] = e0 * inv; ybuf[1] = e1 * inv; ybuf[2] = e2 * inv;
        }
    }

    float wd[9], wu[9];
    #pragma unroll
    for (int k = 0; k < 9; k++) { wd[k] = Wd[k]; wu[k] = Wu[k]; }
    const float bd0 = bd[0], bd1 = bd[1], bd2 = bd[2];
    const float ad0 = ad[0], ad1 = ad[1], ad2 = ad[2];
    const float bu0 = bu[0], bu1 = bu[1], bu2 = bu[2];
    const float au0 = au[0], au1 = au[1], au2 = au[2];
    const float cu0 = prelu(bu0, au0), cu1 = prelu(bu1, au1), cu2 = prelu(bu2, au2);

    // ---- Phase A: stage d1 (17 rows x 65 cols), branch-free aligned float4 loads ----
    // task (r,g): 7 float4 from in1 row 2*min(h0+r,511), px 2*w0b+8g .. +9; compute
    // d1 cols 4g..4g+3 (g==15 also col 64). Max byte read stays inside the buffer:
    // worst row 1022 spills 16B into row 1023 (last row) - in bounds.
    #pragma unroll
    for (int step = 0; step < 2; ++step) {
        const int r = step ? 16 : (tid >> 4);
        const int g = step ? tid : (tid & 15);
        if (step == 0 || tid < 16) {
            const int gh  = h0 + r;
            const int ghc = gh < HW ? gh : (HW - 1);
            const float* rb = in1 + ((size_t)(batch * 1024 + 2 * ghc)) * 3072;
            const int px0 = 2 * w0b + 8 * g;
            const float4* lp = reinterpret_cast<const float4*>(rb + (size_t)px0 * 3);
            float arr[28];
            #pragma unroll
            for (int k = 0; k < 7; ++k)
                *reinterpret_cast<float4*>(&arr[4 * k]) = lp[k];   // all issue back-to-back

            const bool rowOOR = (gh >= HW);
            float* q = d1 + r * PITCH + 12 * g;
            #pragma unroll
            for (int j = 0; j < 4; ++j) {
                const float x0 = arr[6 * j], x1 = arr[6 * j + 1], x2 = arr[6 * j + 2];
                float v0 = prelu(x0 * wd[0] + x1 * wd[3] + x2 * wd[6] + bd0, ad0);
                float v1 = prelu(x0 * wd[1] + x1 * wd[4] + x2 * wd[7] + bd1, ad1);
                float v2 = prelu(x0 * wd[2] + x1 * wd[5] + x2 * wd[8] + bd2, ad2);
                q[3 * j + 0] = rowOOR ? -INFINITY : v0;
                q[3 * j + 1] = rowOOR ? -INFINITY : v1;
                q[3 * j + 2] = rowOOR ? -INFINITY : v2;
            }
            if (g == 15) {   // halo col 64 (px0+8 -> arr[24..26])
                const float x0 = arr[24], x1 = arr[25], x2 = arr[26];
                float v0 = prelu(x0 * wd[0] + x1 * wd[3] + x2 * wd[6] + bd0, ad0);
                float v1 = prelu(x0 * wd[1] + x1 * wd[4] + x2 * wd[7] + bd1, ad1);
                float v2 = prelu(x0 * wd[2] + x1 * wd[5] + x2 * wd[8] + bd2, ad2);
                const bool oor = rowOOR || (w0b + 64 >= HW);
                q[12] = oor ? -INFINITY : v0;
                q[13] = oor ? -INFINITY : v1;
                q[14] = oor ? -INFINITY : v2;
            }
        }
    }
    __syncthreads();

    // ---- Phase B: 4 consecutive px per thread ----
    const int r  = tid >> 4;
    const int cg = tid & 15;
    const int h  = h0 + r;
    const int w0 = w0b + cg * 4;

    // in2: 3 aligned float4
    const float* in2p = in2 + ((size_t)((batch * HW + h) * HW + w0)) * 3;
    float i2v[12];
    #pragma unroll
    for (int k = 0; k < 3; ++k)
        *reinterpret_cast<float4*>(&i2v[4 * k]) = reinterpret_cast<const float4*>(in2p)[k];

    // in3: branch-free clamped loads (9 dwords), validity folded in after
    const int he  = h + (h & 1);
    const bool rOK = he < HW;
    const int hr3 = rOK ? (he >> 1) : 255;
    const int w3  = w0 >> 1;
    float ur[9];
    #pragma unroll
    for (int k = 0; k < 3; ++k) {
        const int wc = (w3 + k < 256) ? (w3 + k) : 255;
        const float* p = in3 + ((size_t)(batch * 256 + hr3) * 256 + wc) * 3;
        ur[3 * k + 0] = p[0]; ur[3 * k + 1] = p[1]; ur[3 * k + 2] = p[2];
    }
    float ud[3][3];
    #pragma unroll
    for (int k = 0; k < 3; ++k) {
        const bool ok = rOK && (w3 + k < 256);
        const float x0 = ur[3 * k], x1 = ur[3 * k + 1], x2 = ur[3 * k + 2];
        const float u0 = prelu(x0 * wu[0] + x1 * wu[3] + x2 * wu[6] + bu0, au0);
        const float u1 = prelu(x0 * wu[1] + x1 * wu[4] + x2 * wu[7] + bu1, au1);
        const float u2 = prelu(x0 * wu[2] + x1 * wu[5] + x2 * wu[8] + bu2, au2);
        ud[k][0] = ok ? fmaxf(cu0, u0) : cu0;
        ud[k][1] = ok ? fmaxf(cu1, u1) : cu1;
        ud[k][2] = ok ? fmaxf(cu2, u2) : cu2;
    }

    // rolling 2x2 maxpool over d1 rows r, r+1
    const int baseA = r * PITCH + cg * 12;
    const int baseB = baseA + PITCH;
    float pA0 = d1[baseA + 0], pA1 = d1[baseA + 1], pA2 = d1[baseA + 2];
    float pB0 = d1[baseB + 0], pB1 = d1[baseB + 1], pB2 = d1[baseB + 2];

    float s[4][3];
    #pragma unroll
    for (int j = 0; j < 4; ++j) {
        const int o = 3 * (j + 1);
        const float cA0 = d1[baseA + o], cA1 = d1[baseA + o + 1], cA2 = d1[baseA + o + 2];
        const float cB0 = d1[baseB + o], cB1 = d1[baseB + o + 1], cB2 = d1[baseB + o + 2];
        const int uk = (j + 1) >> 1;
        s[j][0] = fmaxf(fmaxf(pA0, cA0), fmaxf(pB0, cB0)) + i2v[3 * j + 0] + ud[uk][0];
        s[j][1] = fmaxf(fmaxf(pA1, cA1), fmaxf(pB1, cB1)) + i2v[3 * j + 1] + ud[uk][1];
        s[j][2] = fmaxf(fmaxf(pA2, cA2), fmaxf(pB2, cB2)) + i2v[3 * j + 2] + ud[uk][2];
        pA0 = cA0; pA1 = cA1; pA2 = cA2;
        pB0 = cB0; pB1 = cB1; pB2 = cB2;
    }

    if (MODE == 0) {
        float sum0 = s[0][0] + s[1][0] + s[2][0] + s[3][0];
        float sum1 = s[0][1] + s[1][1] + s[2][1] + s[3][1];
        float sum2 = s[0][2] + s[1][2] + s[2][2] + s[3][2];
        #pragma unroll
        for (int off = 32; off > 0; off >>= 1) {
            sum0 += __shfl_down(sum0, off);
            sum1 += __shfl_down(sum1, off);
            sum2 += __shfl_down(sum2, off);
        }
        if ((tid & 63) == 0) { red[tid >> 6][0] = sum0; red[tid >> 6][1] = sum1; red[tid >> 6][2] = sum2; }
        __syncthreads();
        if (tid == 0) {
            const int pid = (batch * 32 + by) * 8 + bx;
            partials[pid * 3 + 0] = red[0][0] + red[1][0] + red[2][0] + red[3][0];
            partials[pid * 3 + 1] = red[0][1] + red[1][1] + red[2][1] + red[3][1];
            partials[pid * 3 + 2] = red[0][2] + red[1][2] + red[2][2] + red[3][2];
        }
    } else {
        const float ym[3] = { ybuf[0], ybuf[1], ybuf[2] };
        float* outp = out + ((size_t)((batch * HW + h) * HW + w0)) * 3;
        #pragma unroll
        for (int k = 0; k < 3; ++k) {
            float4 v;
            v.x = s[(4 * k + 0) / 3][(4 * k + 0) % 3] * ym[(4 * k + 0) % 3];
            v.y = s[(4 * k + 1) / 3][(4 * k + 1) % 3] * ym[(4 * k + 1) % 3];
            v.z = s[(4 * k + 2) / 3][(4 * k + 2) % 3] * ym[(4 * k + 2) % 3];
            v.w = s[(4 * k + 3) / 3][(4 * k + 3) % 3] * ym[(4 * k + 3) % 3];
            reinterpret_cast<float4*>(outp)[k] = v;
        }
    }
}

extern "C" void kernel_launch(void* const* d_in, const int* in_sizes, int n_in,
                              void* d_out, int out_size, void* d_ws, size_t ws_size,
                              hipStream_t stream)
{
    const float* in1 = (const float*)d_in[0];
    const float* in2 = (const float*)d_in[1];
    const float* in3 = (const float*)d_in[2];
    const float* Wd  = (const float*)d_in[3];
    const float* bd  = (const float*)d_in[4];
    const float* ad  = (const float*)d_in[5];
    const float* Wu  = (const float*)d_in[6];
    const float* bu  = (const float*)d_in[7];
    const float* au  = (const float*)d_in[8];
    const float* Wc  = (const float*)d_in[9];
    const float* bc  = (const float*)d_in[10];
    const float* ag  = (const float*)d_in[11];
    float* out = (float*)d_out;
    float* partials = (float*)d_ws;     // 2048 * 3 floats

    pass_kernel<0><<<dim3(8, 32, 8), 256, 0, stream>>>(in1, in2, in3, Wd, bd, ad, Wu, bu, au,
                                                       partials, Wc, bc, ag, out);
    pass_kernel<1><<<dim3(8, 32, 8), 256, 0, stream>>>(in1, in2, in3, Wd, bd, ad, Wu, bu, au,
                                                       partials, Wc, bc, ag, out);
}